// Round 1
// baseline (1197.384 us; speedup 1.0000x reference)
//
#include <hip/hip_runtime.h>

// Residual VQ: B=8,T=4096,D=128 -> N=32768 rows; 8 codebooks x 1024 codes.
// Outputs concat in d_out (float): codes [N*8], quantized [N*128], loss [1].

#define N_ROWS 32768
#define DIM    128
#define KCB    1024
#define NCB    8
#define MB     64          // rows per block
#define PC     64          // codes per pass
#define NPASS  (KCB / PC)  // 16
#define LDA    132         // padded LDS row stride (floats), 132%8==4 -> conflict-free frags

__global__ __launch_bounds__(256) void zero_ws_kernel(double* lws) {
    if (threadIdx.x < NCB) lws[threadIdx.x] = 0.0;
}

// c2[code] = numpy-pairwise sum over k of cb[code][k]^2 (n=128 pairwise, 8 accums)
__global__ __launch_bounds__(256) void c2_kernel(const float* __restrict__ cbw,
                                                 float* __restrict__ c2g) {
#pragma clang fp contract(off)
    int code = blockIdx.x * 256 + threadIdx.x;  // 0..8191
    const float* row = cbw + (size_t)code * DIM;
    float s[8];
    for (int j = 0; j < 8; ++j) { float x = row[j]; s[j] = x * x; }
    for (int m = 1; m < 16; ++m)
        for (int j = 0; j < 8; ++j) { float x = row[m * 8 + j]; float p = x * x; s[j] += p; }
    c2g[code] = ((s[0] + s[1]) + (s[2] + s[3])) + ((s[4] + s[5]) + (s[6] + s[7]));
}

__global__ __launch_bounds__(256, 2) void rvq_kernel(
    const float* __restrict__ emb, const float* __restrict__ cbw,
    const float* __restrict__ c2g, float* __restrict__ out,
    double* __restrict__ lws)
{
    __shared__ float a_lds[MB * LDA];    // residual [row][k], padded
    __shared__ float b_lds[PC * LDA];    // codebook tile [code][k], padded
    __shared__ float r2_lds[MB];
    __shared__ float c2_lds[PC];
    __shared__ float scr[4 * MB];        // pairwise partials t_q
    __shared__ int   codes_lds[NCB * MB];

    const int tid  = threadIdx.x;
    const int tcol = tid & 15;   // 16 code-columns, codes tcol+16j
    const int trow = tid >> 4;   // 16 row-groups, rows trow+16i
    const size_t base = (size_t)blockIdx.x * MB;

    // ---- stage embeddings -> a_lds (residual) ----
    for (int s = 0; s < 8; ++s) {
        int f4 = s * 256 + tid;          // 0..2047 float4s
        int r = f4 >> 5, k4 = f4 & 31;
        float4 v = *(const float4*)(emb + (base + r) * DIM + (size_t)k4 * 4);
        *(float4*)(a_lds + r * LDA + k4 * 4) = v;
    }
    __syncthreads();

    // ---- initial r2: numpy pairwise (j split across 4 waves: j in {2q,2q+1}) ----
    {
#pragma clang fp contract(off)
        int r = tid & 63, q = tid >> 6;
        float x0 = a_lds[r * LDA + 2 * q];     float s0 = x0 * x0;
        float x1 = a_lds[r * LDA + 2 * q + 1]; float s1 = x1 * x1;
        for (int m = 1; m < 16; ++m) {
            float y0 = a_lds[r * LDA + m * 8 + 2 * q];     float p0 = y0 * y0; s0 += p0;
            float y1 = a_lds[r * LDA + m * 8 + 2 * q + 1]; float p1 = y1 * y1; s1 += p1;
        }
        scr[q * MB + r] = s0 + s1;
    }
    __syncthreads();
    if (tid < MB) {
#pragma clang fp contract(off)
        float t0 = scr[tid], t1 = scr[MB + tid], t2 = scr[2 * MB + tid], t3 = scr[3 * MB + tid];
        r2_lds[tid] = (t0 + t1) + (t2 + t3);
    }
    // (pass-0 barriers below cover r2_lds visibility)

    float minv[4]; int mini[4];

    for (int cb = 0; cb < NCB; ++cb) {
        const float* cbbase = cbw + (size_t)cb * KCB * DIM;
        for (int i = 0; i < 4; ++i) { minv[i] = 3.4e38f; mini[i] = 0; }

        for (int pass = 0; pass < NPASS; ++pass) {
            __syncthreads();  // prior pass's b_lds reads done; r2/a_lds updates visible
            // stage B tile (PC codes) + c2 slice
            const float* bsrc = cbbase + (size_t)pass * PC * DIM;
            for (int s = 0; s < 8; ++s) {
                int f4 = s * 256 + tid;
                int c = f4 >> 5, k4 = f4 & 31;
                float4 v = *(const float4*)(bsrc + (size_t)c * DIM + k4 * 4);
                *(float4*)(b_lds + c * LDA + k4 * 4) = v;
            }
            if (tid < PC) c2_lds[tid] = c2g[cb * KCB + pass * PC + tid];
            __syncthreads();

            // dot products: 4 rows x 4 codes per thread, k ascending (fp32 fma chain)
            float acc[4][4];
            for (int i = 0; i < 4; ++i)
                for (int j = 0; j < 4; ++j) acc[i][j] = 0.f;
#pragma unroll 4
            for (int k4 = 0; k4 < 32; ++k4) {
                float4 av[4], bv[4];
                for (int i = 0; i < 4; ++i)
                    av[i] = *(const float4*)(a_lds + (trow + 16 * i) * LDA + k4 * 4);
                for (int j = 0; j < 4; ++j)
                    bv[j] = *(const float4*)(b_lds + (tcol + 16 * j) * LDA + k4 * 4);
                for (int i = 0; i < 4; ++i)
                    for (int j = 0; j < 4; ++j) {
                        acc[i][j] = fmaf(av[i].x, bv[j].x, acc[i][j]);
                        acc[i][j] = fmaf(av[i].y, bv[j].y, acc[i][j]);
                        acc[i][j] = fmaf(av[i].z, bv[j].z, acc[i][j]);
                        acc[i][j] = fmaf(av[i].w, bv[j].w, acc[i][j]);
                    }
            }
            // epilogue: d2 = fl(fl(r2 - 2*dot) + c2), running argmin (ascending idx)
            {
#pragma clang fp contract(off)
                float r2v[4], c2v[4];
                for (int i = 0; i < 4; ++i) r2v[i] = r2_lds[trow + 16 * i];
                for (int j = 0; j < 4; ++j) c2v[j] = c2_lds[tcol + 16 * j];
                for (int i = 0; i < 4; ++i)
                    for (int j = 0; j < 4; ++j) {
                        float t  = r2v[i] - 2.0f * acc[i][j];
                        float d2 = t + c2v[j];
                        int   cg = pass * PC + tcol + 16 * j;
                        if (d2 < minv[i]) { minv[i] = d2; mini[i] = cg; }
                    }
            }
        }

        // cross-thread argmin over 16 tcols (16-lane butterfly), ties -> lowest index
        for (int i = 0; i < 4; ++i) {
            float v = minv[i]; int ix = mini[i];
            for (int m = 1; m <= 8; m <<= 1) {
                float v2 = __shfl_xor(v, m, 64);
                int  ix2 = __shfl_xor(ix, m, 64);
                if (v2 < v || (v2 == v && ix2 < ix)) { v = v2; ix = ix2; }
            }
            if (tcol == 0) codes_lds[cb * MB + (trow + 16 * i)] = ix;
        }
        __syncthreads();

        // residual update + loss + next-r2 pairwise partials (numpy order preserved)
        {
#pragma clang fp contract(off)
            int r = tid & 63, q = tid >> 6;
            int widx = codes_lds[cb * MB + r];
            const float* ql = cbbase + (size_t)widx * DIM;
            float s0 = 0.f, s1 = 0.f;
            double lacc = 0.0;
            for (int m = 0; m < 16; ++m) {
                int k0 = m * 8 + 2 * q;
                float a0 = a_lds[r * LDA + k0];
                float q0 = ql[k0];
                float n0 = a0 - q0;           // new residual (exact ref op)
                a_lds[r * LDA + k0] = n0;
                float p0 = n0 * n0;           // loss element, fp32-rounded
                if (m == 0) s0 = p0; else s0 += p0;
                lacc += (double)p0;
                int k1 = k0 + 1;
                float a1 = a_lds[r * LDA + k1];
                float q1 = ql[k1];
                float n1 = a1 - q1;
                a_lds[r * LDA + k1] = n1;
                float p1 = n1 * n1;
                if (m == 0) s1 = p1; else s1 += p1;
                lacc += (double)p1;
            }
            scr[q * MB + r] = s0 + s1;
            for (int off = 32; off > 0; off >>= 1) lacc += __shfl_down(lacc, off, 64);
            if ((tid & 63) == 0) atomicAdd(&lws[cb], lacc);
        }
        __syncthreads();
        if (tid < MB) {
#pragma clang fp contract(off)
            float t0 = scr[tid], t1 = scr[MB + tid], t2 = scr[2 * MB + tid], t3 = scr[3 * MB + tid];
            r2_lds[tid] = (t0 + t1) + (t2 + t3);
        }
    }
    __syncthreads();

    // ---- write codes (as float) ----
    if (tid < MB) {
        int r = tid;
        float4 u, v;
        u.x = (float)codes_lds[0 * MB + r]; u.y = (float)codes_lds[1 * MB + r];
        u.z = (float)codes_lds[2 * MB + r]; u.w = (float)codes_lds[3 * MB + r];
        v.x = (float)codes_lds[4 * MB + r]; v.y = (float)codes_lds[5 * MB + r];
        v.z = (float)codes_lds[6 * MB + r]; v.w = (float)codes_lds[7 * MB + r];
        *(float4*)(out + (base + r) * NCB)     = u;
        *(float4*)(out + (base + r) * NCB + 4) = v;
    }

    // ---- quantized = emb + (quant - emb), quant = sequential fp32 sum of codewords ----
    {
#pragma clang fp contract(off)
        int r = tid >> 2, q4 = tid & 3;
        size_t rg = base + r;
        int cds[NCB];
        for (int cb = 0; cb < NCB; ++cb) cds[cb] = codes_lds[cb * MB + r];
        float* qout = out + (size_t)N_ROWS * NCB;
        for (int ii = 0; ii < 8; ++ii) {
            int k = q4 * 32 + ii * 4;
            float4 qv = make_float4(0.f, 0.f, 0.f, 0.f);
            for (int cb = 0; cb < NCB; ++cb) {
                float4 cv = *(const float4*)(cbw + ((size_t)cb * KCB + cds[cb]) * DIM + k);
                qv.x += cv.x; qv.y += cv.y; qv.z += cv.z; qv.w += cv.w;
            }
            float4 ev = *(const float4*)(emb + rg * DIM + k);
            float4 ov;
            ov.x = ev.x + (qv.x - ev.x);
            ov.y = ev.y + (qv.y - ev.y);
            ov.z = ev.z + (qv.z - ev.z);
            ov.w = ev.w + (qv.w - ev.w);
            *(float4*)(qout + rg * DIM + k) = ov;
        }
    }
}

__global__ __launch_bounds__(64) void finish_loss_kernel(const double* __restrict__ lws,
                                                         float* __restrict__ out_loss) {
    if (threadIdx.x == 0 && blockIdx.x == 0) {
        float l = 0.f;
        for (int cb = 0; cb < NCB; ++cb) {
            float m = (float)(lws[cb] / 4194304.0);  // mean over N*D
            l = l + m;                               // fp32 sequential adds (ref order)
        }
        out_loss[0] = l / 8.0f;
    }
}

extern "C" void kernel_launch(void* const* d_in, const int* in_sizes, int n_in,
                              void* d_out, int out_size, void* d_ws, size_t ws_size,
                              hipStream_t stream) {
    const float* emb = (const float*)d_in[0];   // [32768,128] fp32
    const float* cbw = (const float*)d_in[1];   // [8,1024,128] fp32
    float* out = (float*)d_out;
    double* lws = (double*)d_ws;                         // 8 doubles
    float* c2g = (float*)((char*)d_ws + 256);            // 8192 floats

    hipLaunchKernelGGL(zero_ws_kernel, dim3(1), dim3(64), 0, stream, lws);
    hipLaunchKernelGGL(c2_kernel, dim3(32), dim3(256), 0, stream, cbw, c2g);
    hipLaunchKernelGGL(rvq_kernel, dim3(512), dim3(256), 0, stream, emb, cbw, c2g, out, lws);
    hipLaunchKernelGGL(finish_loss_kernel, dim3(1), dim3(64), 0, stream, lws,
                       out + (size_t)N_ROWS * NCB + (size_t)N_ROWS * DIM);
}

// Round 2
// 1106.479 us; speedup vs baseline: 1.0822x; 1.0822x over previous
//
#include <hip/hip_runtime.h>

// Residual VQ: B=8,T=4096,D=128 -> N=32768 rows; 8 codebooks x 1024 codes.
// Outputs concat in d_out (float): codes [N*8], quantized [N*128], loss [1].
// R2: 128x128 block tile, 8x4 per-thread tile, full k-unroll (immediate LDS
// offsets), 512 thr/block, 256 blocks (1 block/CU, 8 waves).

#define N_ROWS 32768
#define DIM    128
#define KCB    1024
#define NCB    8
#define MB     128         // rows per block
#define PC     128         // codes per pass
#define NPASS  (KCB / PC)  // 8
#define LDA    132         // padded LDS row stride (floats)

__global__ __launch_bounds__(256) void zero_ws_kernel(double* lws) {
    if (threadIdx.x < NCB) lws[threadIdx.x] = 0.0;
}

// c2[code] = numpy-pairwise sum over k of cb[code][k]^2 (n=128 pairwise, 8 accums)
__global__ __launch_bounds__(256) void c2_kernel(const float* __restrict__ cbw,
                                                 float* __restrict__ c2g) {
#pragma clang fp contract(off)
    int code = blockIdx.x * 256 + threadIdx.x;  // 0..8191
    const float* row = cbw + (size_t)code * DIM;
    float s[8];
    for (int j = 0; j < 8; ++j) { float x = row[j]; s[j] = x * x; }
    for (int m = 1; m < 16; ++m)
        for (int j = 0; j < 8; ++j) { float x = row[m * 8 + j]; float p = x * x; s[j] += p; }
    c2g[code] = ((s[0] + s[1]) + (s[2] + s[3])) + ((s[4] + s[5]) + (s[6] + s[7]));
}

__global__ __launch_bounds__(512, 2) void rvq_kernel(
    const float* __restrict__ emb, const float* __restrict__ cbw,
    const float* __restrict__ c2g, float* __restrict__ out,
    double* __restrict__ lws)
{
    __shared__ float a_lds[MB * LDA];    // residual [row][k], padded  (67584 B)
    __shared__ float b_lds[PC * LDA];    // codebook tile [code][k]    (67584 B)
    __shared__ float r2_lds[MB];
    __shared__ float c2_lds[PC];
    __shared__ float scr[4 * MB];        // pairwise partials
    __shared__ int   codes_lds[NCB * MB];

    const int tid  = threadIdx.x;
    const int tcol = tid & 31;   // 32 code-columns: codes tcol+32j, j<4
    const int trow = tid >> 5;   // 16 row-groups: rows trow+16i, i<8
    const size_t base = (size_t)blockIdx.x * MB;

    // ---- stage embeddings -> a_lds (residual) ----
    for (int s = 0; s < 8; ++s) {
        int f4 = s * 512 + tid;          // 0..4095 float4s
        int r = f4 >> 5, k4 = f4 & 31;
        float4 v = *(const float4*)(emb + (base + r) * DIM + (size_t)k4 * 4);
        *(float4*)(a_lds + r * LDA + k4 * 4) = v;
    }
    __syncthreads();

    // ---- initial r2: numpy pairwise (8 accums s_j; thread handles j in {2q,2q+1}) ----
    {
#pragma clang fp contract(off)
        int r = tid & 127, q = tid >> 7;   // q in 0..3
        float x0 = a_lds[r * LDA + 2 * q];     float s0 = x0 * x0;
        float x1 = a_lds[r * LDA + 2 * q + 1]; float s1 = x1 * x1;
        for (int m = 1; m < 16; ++m) {
            float y0 = a_lds[r * LDA + m * 8 + 2 * q];     float p0 = y0 * y0; s0 += p0;
            float y1 = a_lds[r * LDA + m * 8 + 2 * q + 1]; float p1 = y1 * y1; s1 += p1;
        }
        scr[q * MB + r] = s0 + s1;
    }
    __syncthreads();
    if (tid < MB) {
#pragma clang fp contract(off)
        float t0 = scr[tid], t1 = scr[MB + tid], t2 = scr[2 * MB + tid], t3 = scr[3 * MB + tid];
        r2_lds[tid] = (t0 + t1) + (t2 + t3);
    }
    // (pass-0 barrier below covers r2_lds visibility)

    const float* ab = a_lds + trow * LDA;
    const float* bb = b_lds + tcol * LDA;

    float minv[8]; int mini[8];

    for (int cb = 0; cb < NCB; ++cb) {
        const float* cbbase = cbw + (size_t)cb * KCB * DIM;
        for (int i = 0; i < 8; ++i) { minv[i] = 3.4e38f; mini[i] = 0; }

        for (int pass = 0; pass < NPASS; ++pass) {
            __syncthreads();  // prior pass's b_lds reads done; r2/a_lds updates visible
            // stage B tile (PC codes) + c2 slice
            const float* bsrc = cbbase + (size_t)pass * PC * DIM;
            for (int s = 0; s < 8; ++s) {
                int f4 = s * 512 + tid;      // 0..4095
                int c = f4 >> 5, k4 = f4 & 31;
                float4 v = *(const float4*)(bsrc + (size_t)c * DIM + k4 * 4);
                *(float4*)(b_lds + c * LDA + k4 * 4) = v;
            }
            if (tid < PC) c2_lds[tid] = c2g[cb * KCB + pass * PC + tid];
            __syncthreads();

            // dots: 8 rows x 4 codes per thread, k ascending fp32 fma chains.
            // Full unroll -> every ds_read uses an immediate offset off the two
            // fixed base pointers (max offset 112*528+496 < 64 KiB).
            float acc[8][4];
            for (int i = 0; i < 8; ++i)
                for (int j = 0; j < 4; ++j) acc[i][j] = 0.f;
#pragma unroll
            for (int k4 = 0; k4 < 32; ++k4) {
                float4 av[8], bv[4];
#pragma unroll
                for (int i = 0; i < 8; ++i)
                    av[i] = *(const float4*)(ab + i * 16 * LDA + k4 * 4);
#pragma unroll
                for (int j = 0; j < 4; ++j)
                    bv[j] = *(const float4*)(bb + j * 32 * LDA + k4 * 4);
#pragma unroll
                for (int i = 0; i < 8; ++i)
#pragma unroll
                    for (int j = 0; j < 4; ++j) {
                        acc[i][j] = fmaf(av[i].x, bv[j].x, acc[i][j]);
                        acc[i][j] = fmaf(av[i].y, bv[j].y, acc[i][j]);
                        acc[i][j] = fmaf(av[i].z, bv[j].z, acc[i][j]);
                        acc[i][j] = fmaf(av[i].w, bv[j].w, acc[i][j]);
                    }
            }
            // epilogue: d2 = fl(fl(r2 - 2*dot) + c2), running argmin (ascending idx)
            {
#pragma clang fp contract(off)
                float r2v[8], c2v[4];
                for (int i = 0; i < 8; ++i) r2v[i] = r2_lds[trow + 16 * i];
                for (int j = 0; j < 4; ++j) c2v[j] = c2_lds[tcol + 32 * j];
                for (int i = 0; i < 8; ++i)
                    for (int j = 0; j < 4; ++j) {
                        float t  = r2v[i] - 2.0f * acc[i][j];
                        float d2 = t + c2v[j];
                        int   cg = pass * PC + tcol + 32 * j;
                        if (d2 < minv[i]) { minv[i] = d2; mini[i] = cg; }
                    }
            }
        }

        // cross-thread argmin over 32 tcols (lanes tid&31 within half-wave),
        // ties -> lowest index
        for (int i = 0; i < 8; ++i) {
            float v = minv[i]; int ix = mini[i];
            for (int m = 1; m <= 16; m <<= 1) {
                float v2 = __shfl_xor(v, m, 64);
                int  ix2 = __shfl_xor(ix, m, 64);
                if (v2 < v || (v2 == v && ix2 < ix)) { v = v2; ix = ix2; }
            }
            if (tcol == 0) codes_lds[cb * MB + (trow + 16 * i)] = ix;
        }
        __syncthreads();

        // residual update + loss + next-r2 pairwise partials (numpy order preserved)
        {
#pragma clang fp contract(off)
            int r = tid & 127, q = tid >> 7;
            int widx = codes_lds[cb * MB + r];
            const float* ql = cbbase + (size_t)widx * DIM;
            float s0 = 0.f, s1 = 0.f;
            double lacc = 0.0;
            for (int m = 0; m < 16; ++m) {
                int k0 = m * 8 + 2 * q;
                float a0 = a_lds[r * LDA + k0];
                float q0 = ql[k0];
                float n0 = a0 - q0;           // new residual (exact ref op)
                a_lds[r * LDA + k0] = n0;
                float p0 = n0 * n0;           // loss element, fp32-rounded
                if (m == 0) s0 = p0; else s0 += p0;
                lacc += (double)p0;
                int k1 = k0 + 1;
                float a1 = a_lds[r * LDA + k1];
                float q1 = ql[k1];
                float n1 = a1 - q1;
                a_lds[r * LDA + k1] = n1;
                float p1 = n1 * n1;
                if (m == 0) s1 = p1; else s1 += p1;
                lacc += (double)p1;
            }
            scr[q * MB + r] = s0 + s1;
            for (int off = 32; off > 0; off >>= 1) lacc += __shfl_down(lacc, off, 64);
            if ((tid & 63) == 0) atomicAdd(&lws[cb], lacc);
        }
        __syncthreads();
        if (tid < MB) {
#pragma clang fp contract(off)
            float t0 = scr[tid], t1 = scr[MB + tid], t2 = scr[2 * MB + tid], t3 = scr[3 * MB + tid];
            r2_lds[tid] = (t0 + t1) + (t2 + t3);
        }
    }
    __syncthreads();

    // ---- write codes (as float) ----
    if (tid < MB) {
        int r = tid;
        float4 u, v;
        u.x = (float)codes_lds[0 * MB + r]; u.y = (float)codes_lds[1 * MB + r];
        u.z = (float)codes_lds[2 * MB + r]; u.w = (float)codes_lds[3 * MB + r];
        v.x = (float)codes_lds[4 * MB + r]; v.y = (float)codes_lds[5 * MB + r];
        v.z = (float)codes_lds[6 * MB + r]; v.w = (float)codes_lds[7 * MB + r];
        *(float4*)(out + (base + r) * NCB)     = u;
        *(float4*)(out + (base + r) * NCB + 4) = v;
    }

    // ---- quantized = emb + (quant - emb), quant = sequential fp32 sum of codewords ----
    {
#pragma clang fp contract(off)
        int r = tid >> 2, q4 = tid & 3;
        size_t rg = base + r;
        int cds[NCB];
        for (int cb = 0; cb < NCB; ++cb) cds[cb] = codes_lds[cb * MB + r];
        float* qout = out + (size_t)N_ROWS * NCB;
        for (int ii = 0; ii < 8; ++ii) {
            int k = q4 * 32 + ii * 4;
            float4 qv = make_float4(0.f, 0.f, 0.f, 0.f);
            for (int cb = 0; cb < NCB; ++cb) {
                float4 cv = *(const float4*)(cbw + ((size_t)cb * KCB + cds[cb]) * DIM + k);
                qv.x += cv.x; qv.y += cv.y; qv.z += cv.z; qv.w += cv.w;
            }
            float4 ev = *(const float4*)(emb + rg * DIM + k);
            float4 ov;
            ov.x = ev.x + (qv.x - ev.x);
            ov.y = ev.y + (qv.y - ev.y);
            ov.z = ev.z + (qv.z - ev.z);
            ov.w = ev.w + (qv.w - ev.w);
            *(float4*)(qout + rg * DIM + k) = ov;
        }
    }
}

__global__ __launch_bounds__(64) void finish_loss_kernel(const double* __restrict__ lws,
                                                         float* __restrict__ out_loss) {
    if (threadIdx.x == 0 && blockIdx.x == 0) {
        float l = 0.f;
        for (int cb = 0; cb < NCB; ++cb) {
            float m = (float)(lws[cb] / 4194304.0);  // mean over N*D
            l = l + m;                               // fp32 sequential adds (ref order)
        }
        out_loss[0] = l / 8.0f;
    }
}

extern "C" void kernel_launch(void* const* d_in, const int* in_sizes, int n_in,
                              void* d_out, int out_size, void* d_ws, size_t ws_size,
                              hipStream_t stream) {
    const float* emb = (const float*)d_in[0];   // [32768,128] fp32
    const float* cbw = (const float*)d_in[1];   // [8,1024,128] fp32
    float* out = (float*)d_out;
    double* lws = (double*)d_ws;                         // 8 doubles
    float* c2g = (float*)((char*)d_ws + 256);            // 8192 floats

    hipLaunchKernelGGL(zero_ws_kernel, dim3(1), dim3(64), 0, stream, lws);
    hipLaunchKernelGGL(c2_kernel, dim3(32), dim3(256), 0, stream, cbw, c2g);
    hipLaunchKernelGGL(rvq_kernel, dim3(256), dim3(512), 0, stream, emb, cbw, c2g, out, lws);
    hipLaunchKernelGGL(finish_loss_kernel, dim3(1), dim3(64), 0, stream, lws,
                       out + (size_t)N_ROWS * NCB + (size_t)N_ROWS * DIM);
}